// Round 9
// baseline (4074.193 us; speedup 1.0000x reference)
//
#include <hip/hip_runtime.h>
#include <math.h>

#define NDATA   20000
#define DFEAT   1024
#define TWO_M   64
#define MM      32
#define ETA_F   1e-4f
#define THRES_F 1e-12f
#define NSWEEP  8
#define NBLK    256
#define NTHR    1024
#define NW      (NBLK*(NTHR/64))
#define BIGF    3.0e38f

// ---- ws layout (bytes) ----
#define O_CTL    0         // int[16]; bar @128, gen @192 (separate lines)
#define O_CNT    256       // int[256]
#define O_ACCT   1280      // int[64]
#define O_ACCK   1536      // float[64]
#define O_TTIME  1792      // int[64]
#define O_BT     2048      // float[64*1024]
#define O_BASE   264192    // float[20000]
#define O_SCV    344192    // float[20000]
#define O_FLAG   424192    // int[20000]
#define O_CL0    504192    // int[20000]
#define O_LA     584192    // int[20000]
#define O_LB     664192    // int[20000]
#define O_CHT    744192    // int[1024]
#define O_CHB    748288    // float[1024]
#define O_CHS    752384    // float[1024]
#define O_D      756480    // float[CHV*CHV]

#define C_NACC 0
#define C_RC   1
#define C_SHR  2
#define C_TS   3
#define C_RCA  4
#define C_DONE 5

// jacobi LDS mapping inside SH[32832]
#define TG(r,c)     SH[(r)*257 + (c)]
#define SG(cb,idx)  SH[16448 + (cb)*4096 + (idx)]
#define SU(cb,idx)  SH[24640 + (cb)*4096 + (idx)]

#define LD_SLICE(P,v0,v1,v2,v3) do { v0=(P)[lane]; v1=(P)[lane+64]; v2=(P)[lane+128]; v3=(P)[lane+192]; } while(0)

__device__ __forceinline__ float wave_sum(float v) {
    v += __shfl_xor(v, 1);  v += __shfl_xor(v, 2);  v += __shfl_xor(v, 4);
    v += __shfl_xor(v, 8);  v += __shfl_xor(v, 16); v += __shfl_xor(v, 32);
    return v;
}
__device__ __forceinline__ int wave_min_i(int v) {
    v = min(v, __shfl_xor(v, 1));  v = min(v, __shfl_xor(v, 2));
    v = min(v, __shfl_xor(v, 4));  v = min(v, __shfl_xor(v, 8));
    v = min(v, __shfl_xor(v, 16)); v = min(v, __shfl_xor(v, 32));
    return v;
}
__device__ __forceinline__ void pair_from(int p, int &a, int &b) {
    int a_ = 0, rem = p;
    while (rem >= 64 - a_) { rem -= 64 - a_; ++a_; }
    a = a_; b = a_ + rem;
}
__device__ __forceinline__ float dot16(float4 x0, float4 x1, float4 x2, float4 x3,
                                       float4 y0, float4 y1, float4 y2, float4 y3) {
    float d = x0.x*y0.x + x0.y*y0.y + x0.z*y0.z + x0.w*y0.w;
    d += x1.x*y1.x + x1.y*y1.y + x1.z*y1.z + x1.w*y1.w;
    d += x2.x*y2.x + x2.y*y2.y + x2.z*y2.z + x2.w*y2.w;
    d += x3.x*y3.x + x3.y*y3.y + x3.z*y3.z + x3.w*y3.w;
    return d;
}
__device__ __forceinline__ int lbound(const int* arr, int n, int key) {
    int lo = 0, hi = n;
    while (lo < hi) { int mid = (lo + hi) >> 1; if (arr[mid] > key) hi = mid; else lo = mid + 1; }
    return lo;
}

// ---- custom grid barrier: sense-reversing, agent-scope ----
__device__ __forceinline__ void gbar(int* __restrict__ bar, int* __restrict__ gen) {
    __threadfence();                                   // publish this thread's writes
    __syncthreads();
    if (threadIdx.x == 0) {
        int g = __hip_atomic_load(gen, __ATOMIC_RELAXED, __HIP_MEMORY_SCOPE_AGENT);
        int a = __hip_atomic_fetch_add(bar, 1, __ATOMIC_ACQ_REL, __HIP_MEMORY_SCOPE_AGENT);
        if (a == NBLK - 1) {
            __hip_atomic_store(bar, 0, __ATOMIC_RELAXED, __HIP_MEMORY_SCOPE_AGENT);
            __hip_atomic_store(gen, g + 1, __ATOMIC_RELEASE, __HIP_MEMORY_SCOPE_AGENT);
        } else {
            while (__hip_atomic_load(gen, __ATOMIC_ACQUIRE, __HIP_MEMORY_SCOPE_AGENT) == g)
                __builtin_amdgcn_s_sleep(1);
        }
    }
    __syncthreads();
    __builtin_amdgcn_fence(__ATOMIC_ACQUIRE, "agent"); // all threads see others' writes
}

// wave-parallel: prefix = sum(counts[0..bid)), total = sum(counts[0..256))
__device__ __forceinline__ void counts_scan(const int* __restrict__ counts, int bid, int lane,
                                            int* prefix_out, int* total_out) {
    const int4 c4 = ((const int4*)counts)[lane];
    int s = c4.x + c4.y + c4.z + c4.w;
    int inc = s;
    for (int off = 1; off < 64; off <<= 1) {
        int o = __shfl_up(inc, off);
        if (lane >= off) inc += o;
    }
    int total = __shfl(inc, 63);
    int lanepre = inc - s;
    int L = bid >> 2, r = bid & 3;
    int grouppre = __shfl(lanepre, L);
    int4 cg = ((const int4*)counts)[L];
    int part = (r > 0 ? cg.x : 0) + (r > 1 ? cg.y : 0) + (r > 2 ? cg.z : 0);
    *prefix_out = grouppre + part;
    *total_out  = total;
}

// out[t] = base[t] + sum_{j in [jlo,jhi], ttime[j] < t} (Bt_j . alpha_t)^2
__device__ void finalize_range(const float* __restrict__ A, const float* __restrict__ base,
                               const float* __restrict__ Bt, const int* __restrict__ ttime,
                               float* __restrict__ out,
                               int lo, int hi, int jlo, int jhi, int gw, int lane)
{
    for (int t = lo + gw; t <= hi; t += NW) {
        const float4* At = (const float4*)(A + (size_t)t * DFEAT);
        float4 a0, a1, a2, a3; LD_SLICE(At, a0, a1, a2, a3);
        float o = base[t];
        for (int jc = jlo; jc <= jhi; ++jc) {
            if (ttime[jc] >= t) break;
            const float4* Bj = (const float4*)(Bt + (size_t)jc * DFEAT);
            float4 b0, b1, b2, b3; LD_SLICE(Bj, b0, b1, b2, b3);
            float d = dot16(a0, a1, a2, a3, b0, b1, b2, b3);
            d = wave_sum(d);
            o += d * d;
        }
        if (lane == 0) out[t] = o;
    }
}

// pairwise dots of chunk rows; coverage for any wave count
template<int CHV>
__device__ void build_D(const float* __restrict__ A, const int* __restrict__ listP,
                        int clen, float* __restrict__ D, int wave_id, int n_waves, int lane)
{
    const int WPR = 4;
    for (int ii = wave_id; ii < clen * WPR; ii += n_waves) {
        int i = ii >> 2, of = ii & 3;
        const float4* Ai = (const float4*)(A + (size_t)listP[i] * DFEAT);
        float4 a0, a1, a2, a3; LD_SLICE(Ai, a0, a1, a2, a3);
        for (int j = i + 1 + of; j < clen; j += WPR) {
            const float4* Aj = (const float4*)(A + (size_t)listP[j] * DFEAT);
            float4 b0, b1, b2, b3; LD_SLICE(Aj, b0, b1, b2, b3);
            float d = dot16(a0, a1, a2, a3, b0, b1, b2, b3);
            d = wave_sum(d);
            if (lane == 0) D[(size_t)i * CHV + j] = d;
        }
    }
}

// fold accepted cols into survivors' scv, set flags, chunk meta, per-block counts, build D
template<int CHV>
__device__ void phase_prepare(const float* __restrict__ A, const float* __restrict__ Y,
                              float* __restrict__ scv, int* __restrict__ flag,
                              const int* __restrict__ listP, int lenL,
                              const int* __restrict__ accT, const float* __restrict__ accK, int nacc,
                              int* __restrict__ chT, float* __restrict__ chB, float* __restrict__ chS,
                              float* __restrict__ D, int* __restrict__ counts,
                              float* SH, int* s_cnt,
                              int bid, int tid, int wv, int lane, int gw)
{
    int clen = min(lenL, CHV);
    for (int i = bid * NTHR + tid; i < clen; i += NBLK * NTHR) {
        int t = listP[i];
        chT[i] = t;
        chB[i] = Y[t];
    }
    const int hs = (CHV + NBLK - 1) / NBLK;
    int h0 = min(bid * hs, clen), h1 = min(h0 + hs, clen);
    int tailLen = lenL > CHV ? lenL - CHV : 0;
    int ts2 = (tailLen + NBLK - 1) / NBLK;
    int t0 = CHV + min(bid * ts2, tailLen), t1 = min(t0 + ts2, lenL);
    if (tid == 0) *s_cnt = 0;
    __syncthreads();

    for (int jb = 0; jb < nacc; jb += 16) {
        int nj = min(16, nacc - jb);
        if (wv < nj) {
            const float4* Ar = (const float4*)(A + (size_t)accT[jb + wv] * DFEAT);
            float4* S4 = (float4*)SH;
            for (int q = 0; q < 4; ++q) S4[wv * 256 + lane + 64 * q] = Ar[lane + 64 * q];
        }
        __syncthreads();
        const float4* S4 = (const float4*)SH;
        for (int pass = 0; pass < 2; ++pass) {
            int lo = pass ? t0 : h0, hi = pass ? t1 : h1;
            for (int e = lo + wv; e < hi; e += 16) {
                int t = listP[e];
                const float4* At = (const float4*)(A + (size_t)t * DFEAT);
                float4 a0, a1, a2, a3; LD_SLICE(At, a0, a1, a2, a3);
                float cacc = 0.f;
                for (int j = 0; j < nj; ++j) {
                    float d = dot16(a0, a1, a2, a3,
                                    S4[j*256+lane], S4[j*256+lane+64],
                                    S4[j*256+lane+128], S4[j*256+lane+192]);
                    d = wave_sum(d);
                    float v = accK[jb + j] * d;
                    cacc += v * v;
                }
                if (lane == 0) scv[t] += cacc;
            }
        }
        __syncthreads();
    }

    for (int e = h0 + tid; e < h1; e += NTHR) {
        int t = listP[e];
        float sc = scv[t];
        int alive = (sc <= Y[t]) ? 1 : 0;
        flag[t] = alive;
        chS[e] = alive ? sc : BIGF;
    }
    for (int e = t0 + tid; e < t1; e += NTHR) {
        int t = listP[e];
        float sc = scv[t];
        int alive = (sc <= Y[t]) ? 1 : 0;
        flag[t] = alive;
        if (alive) atomicAdd(s_cnt, 1);
    }
    __syncthreads();
    if (tid == 0) counts[bid] = *s_cnt;

    build_D<CHV>(A, listP, clen, D, gw, NW, lane);
}

// order-preserving scatter of tail survivors -> listNxt; returns total survivors
template<int CHV>
__device__ int scatter_and_total(const int* __restrict__ listCur, int lenCur,
                                 const int* __restrict__ flag, const int* __restrict__ counts,
                                 int* __restrict__ listNxt, int bid, int tid, int wv, int lane)
{
    int tailLen = lenCur > CHV ? lenCur - CHV : 0;
    int ts2 = (tailLen + NBLK - 1) / NBLK;
    int e0 = min(bid * ts2, tailLen), e1 = min(e0 + ts2, tailLen);
    int pre, tot;
    counts_scan(counts, bid, lane, &pre, &tot);
    if (wv == 0 && e1 > e0) {
        int dst = pre;
        for (int w0 = e0; w0 < e1; w0 += 64) {
            int idx = w0 + lane;
            int tt = 0, fl = 0;
            if (idx < e1) { tt = listCur[CHV + idx]; fl = flag[tt]; }
            unsigned long long mb = __ballot(fl);
            int pos = (int)__popcll(mb & ((1ull << lane) - 1ull));
            if (fl) listNxt[dst + pos] = tt;
            dst += (int)__popcll(mb);
        }
    }
    return tot;
}

// block-0 sequential chunk resolution via D
template<int CHV>
__device__ void resolve_blk0(const float* __restrict__ A, float* __restrict__ Bt,
                             int* __restrict__ ttime,
                             const int* __restrict__ chT, const float* __restrict__ chB,
                             const float* __restrict__ chS, const float* __restrict__ D,
                             int* __restrict__ ctl, int* __restrict__ accT, float* __restrict__ accK,
                             int chunkLen, int tailTotal,
                             float* accL, float* bbL, int* s_red, int* s_imin,
                             int* accTl, float* accKl, int tid, int wv, int lane)
{
    int rc0 = ctl[C_RC];
    if (tid < CHV) {
        accL[tid] = (tid < chunkLen) ? chS[tid] : BIGF;
        bbL[tid]  = (tid < chunkLen) ? chB[tid] : -BIGF;
    }
    __syncthreads();
    int rcl = rc0, naccL = 0, shr = 0, tsv = NDATA;
    for (;;) {
        int cand = 0x7FFFFFFF;
        if (tid < chunkLen && accL[tid] <= bbL[tid]) cand = tid;
        cand = wave_min_i(cand);
        if (lane == 0) s_red[wv] = cand;
        __syncthreads();
        if (wv == 0) {
            int v = (lane < 16) ? s_red[lane] : 0x7FFFFFFF;
            v = wave_min_i(v);
            if (lane == 0) *s_imin = v;
        }
        __syncthreads();
        int im = *s_imin;
        if (im == 0x7FFFFFFF) break;
        float sc = accL[im], b = bbL[im];
        float kap = sqrtf(2.f * ETA_F * (b - sc));
        __syncthreads();
        rcl += 1;
        if (tid == 0) { accTl[naccL] = chT[im]; accKl[naccL] = kap; }
        naccL += 1;
        if (tid > im && tid < chunkLen) {
            float dv = D[(size_t)im * CHV + tid];
            float v = kap * dv;
            accL[tid] += v * v;
        }
        if (tid <= im && tid < CHV) accL[tid] = BIGF;
        if (rcl == TWO_M - 1) { shr = 1; tsv = chT[im]; }
        __syncthreads();
        if (shr) break;
    }
    __syncthreads();
    for (int q = 0; q < naccL; ++q) {
        int colr = rc0 + 1 + q;
        int tq = accTl[q];
        float kq = accKl[q];
        Bt[(size_t)colr * DFEAT + tid] = kq * A[(size_t)tq * DFEAT + tid];
        if (tid == 0) ttime[colr] = tq;
    }
    if (tid < naccL) { accT[tid] = accTl[tid]; accK[tid] = accKl[tid]; }
    if (tid == 0) {
        ctl[C_NACC] = naccL;
        ctl[C_RC]   = rcl;
        ctl[C_SHR]  = shr;
        ctl[C_TS]   = tsv;
        ctl[C_DONE] = (!shr && naccL == 0 && tailTotal == 0) ? 1 : 0;
    }
}

// block-0 FD shrink: Gram -> tournament Jacobi -> sort -> remix Bt
__device__ void jacobi_shrink(float* __restrict__ Bt, int* __restrict__ ctl, float* SH,
                              float* s_rotA, float* s_rotB, int* s_prt,
                              float* s_S, float* s_Ss, int* s_perm, int* s_misc, int tid)
{
    float acc0 = 0.f, acc1 = 0.f, acc2 = 0.f;
    int a0i, b0i, a1i, b1i, a2i, b2i;
    pair_from(tid, a0i, b0i);
    pair_from(tid + 1024, a1i, b1i);
    pair_from((tid < 32) ? (tid + 2048) : 0, a2i, b2i);
    for (int c = 0; c < 4; ++c) {
        __syncthreads();
        for (int q = tid; q < 64 * 64; q += NTHR) {
            int jj = q >> 6, d4 = q & 63;
            float4 v = ((const float4*)(Bt + (size_t)jj * DFEAT + c * 256))[d4];
            TG(jj, d4*4+0) = v.x; TG(jj, d4*4+1) = v.y;
            TG(jj, d4*4+2) = v.z; TG(jj, d4*4+3) = v.w;
        }
        __syncthreads();
        for (int dd = 0; dd < 256; ++dd) {
            acc0 += TG(a0i, dd) * TG(b0i, dd);
            acc1 += TG(a1i, dd) * TG(b1i, dd);
            acc2 += TG(a2i, dd) * TG(b2i, dd);
        }
    }
    SG(0, a0i*64+b0i) = acc0; SG(0, b0i*64+a0i) = acc0;
    SG(0, a1i*64+b1i) = acc1; SG(0, b1i*64+a1i) = acc1;
    if (tid < 32) { SG(0, a2i*64+b2i) = acc2; SG(0, b2i*64+a2i) = acc2; }
    for (int e4 = 0; e4 < 4; ++e4) {
        int e = tid + e4 * 1024;
        SU(0, e) = ((e >> 6) == (e & 63)) ? 1.f : 0.f;
    }
    __syncthreads();

    int cur = 0;
    for (int sw = 0; sw < NSWEEP; ++sw) {
        for (int r = 0; r < 63; ++r) {
            if (tid < 32) {
                int p_, q_;
                if (tid == 0) { p_ = 63; q_ = r; }
                else { p_ = (r + tid) % 63; q_ = (r + 63 - tid) % 63; }
                float gpp = SG(cur, p_*64+p_);
                float gqq = SG(cur, q_*64+q_);
                float gpq = SG(cur, p_*64+q_);
                float cc = 1.f, sn = 0.f;
                if (fabsf(gpq) > 1e-20f) {
                    float tau = (gqq - gpp) / (2.f * gpq);
                    float tt  = (tau >= 0.f ? 1.f : -1.f) / (fabsf(tau) + sqrtf(1.f + tau * tau));
                    cc = 1.f / sqrtf(1.f + tt * tt);
                    sn = tt * cc;
                }
                s_rotA[p_] = cc; s_rotB[p_] = -sn; s_prt[p_] = q_;
                s_rotA[q_] = cc; s_rotB[q_] = sn;  s_prt[q_] = p_;
            }
            __syncthreads();
            float ng[4], nu[4];
            for (int e4 = 0; e4 < 4; ++e4) {
                int e = tid + e4 * 1024;
                int row = e >> 6, col = e & 63;
                int pr = s_prt[row], pc = s_prt[col];
                float ar = s_rotA[row], br = s_rotB[row];
                float ac = s_rotA[col], bc = s_rotB[col];
                ng[e4] = ar*ac*SG(cur, row*64+col) + br*ac*SG(cur, pr*64+col)
                       + ar*bc*SG(cur, row*64+pc)  + br*bc*SG(cur, pr*64+pc);
                nu[e4] = ac*SU(cur, row*64+col) + bc*SU(cur, row*64+pc);
            }
            for (int e4 = 0; e4 < 4; ++e4) {
                int e = tid + e4 * 1024;
                SG(cur ^ 1, e) = ng[e4];
                SU(cur ^ 1, e) = nu[e4];
            }
            __syncthreads();
            cur ^= 1;
        }
    }

    if (tid < 64) {
        float lam = SG(cur, tid*64+tid);
        if (lam <= THRES_F) lam = 0.f;
        s_S[tid] = lam;
    }
    __syncthreads();
    if (tid < 64) {
        float my = s_S[tid];
        int rank = 0;
        for (int i = 0; i < 64; ++i) {
            float o = s_S[i];
            rank += ((o > my) || (o == my && i < tid)) ? 1 : 0;
        }
        s_perm[rank] = tid;
        s_Ss[rank]   = my;
    }
    __syncthreads();
    if (tid == 0) {
        int nz = 0;
        for (int i = 0; i < 64; ++i) nz += (s_Ss[i] > 0.f) ? 1 : 0;
        s_misc[0] = nz;
        s_misc[1] = (nz >= MM) ? 1 : 0;
    }
    __syncthreads();
    const int nnz = s_misc[0];
    const int ge  = s_misc[1];
    const float S32 = s_Ss[MM];

    for (int e4 = 0; e4 < 4; ++e4) {
        int e = tid + e4 * 1024;
        int kk = e >> 6, jn = e & 63;
        float Sj = s_Ss[jn];
        float f;
        if (ge) f = (jn < MM - 1 && Sj > 0.f) ? sqrtf(fmaxf(Sj - S32, 0.f) / Sj) : 0.f;
        else    f = (jn < nnz) ? 1.f : 0.f;
        SG(0, kk*64+jn) = SU(cur, kk*64 + s_perm[jn]) * f;
    }
    __syncthreads();

    for (int c = 0; c < 4; ++c) {
        __syncthreads();
        for (int q = tid; q < 64 * 64; q += NTHR) {
            int jj = q >> 6, d4 = q & 63;
            float4 v = ((const float4*)(Bt + (size_t)jj * DFEAT + c * 256))[d4];
            TG(jj, d4*4+0) = v.x; TG(jj, d4*4+1) = v.y;
            TG(jj, d4*4+2) = v.z; TG(jj, d4*4+3) = v.w;
        }
        __syncthreads();
        for (int q = tid; q < 64 * 256; q += NTHR) {
            int dd = q & 255, jn = q >> 8;
            float sum = 0.f;
            for (int kk = 0; kk < 64; ++kk)
                sum += TG(kk, dd) * SG(0, kk*64+jn);
            Bt[(size_t)jn * DFEAT + c * 256 + dd] = sum;
        }
    }
    __syncthreads();
    if (tid == 0) {
        int rcn = ge ? (MM - 1) : nnz;
        ctl[C_RCA] = rcn;
        ctl[C_RC]  = rcn;
    }
}

// post-shrink: scv/base/flag for all rows t > ts, Bt staged in LDS halves
__device__ void recompute_rows(const float* __restrict__ A, const float* __restrict__ Y,
                               const float* __restrict__ Bt,
                               float* __restrict__ scv, float* __restrict__ base,
                               int* __restrict__ flag, int ts,
                               float* SH, int tid, int wv, int lane, int gw)
{
    int nrows = NDATA - 1 - ts;
    int npair = (nrows + 1) >> 1;
    for (int h = 0; h < 2; ++h) {
        {
            const float4* B4 = (const float4*)Bt;
            float4* S4 = (float4*)SH;
            for (int q = 0; q < 4; ++q) {
                S4[wv * 256 + lane + 64*q]      = B4[(size_t)(h*32 + wv) * 256 + lane + 64*q];
                S4[(wv+16) * 256 + lane + 64*q] = B4[(size_t)(h*32 + wv + 16) * 256 + lane + 64*q];
            }
        }
        __syncthreads();
        const float4* S4 = (const float4*)SH;
        for (int p = gw; p < npair; p += NW) {
            int tA = ts + 1 + 2*p;
            int tB = tA + 1;
            bool hasB = tB < NDATA;
            const float4* Aa = (const float4*)(A + (size_t)tA * DFEAT);
            float4 x0, x1, x2, x3; LD_SLICE(Aa, x0, x1, x2, x3);
            float4 y0 = make_float4(0,0,0,0), y1 = y0, y2 = y0, y3 = y0;
            if (hasB) {
                const float4* Ab = (const float4*)(A + (size_t)tB * DFEAT);
                LD_SLICE(Ab, y0, y1, y2, y3);
            }
            float s1 = 0.f, s2 = 0.f;
            for (int j = 0; j < 32; ++j) {
                float4 b0 = S4[j*256+lane],     b1 = S4[j*256+lane+64],
                       b2 = S4[j*256+lane+128], b3 = S4[j*256+lane+192];
                float d1 = dot16(x0,x1,x2,x3,b0,b1,b2,b3);
                d1 = wave_sum(d1);
                s1 += d1 * d1;
                float d2 = dot16(y0,y1,y2,y3,b0,b1,b2,b3);
                d2 = wave_sum(d2);
                s2 += d2 * d2;
            }
            if (lane == 0) {
                if (h == 0) {
                    scv[tA] = s1;
                    if (hasB) scv[tB] = s2;
                } else {
                    float f1 = scv[tA] + s1;
                    scv[tA] = f1; base[tA] = f1; flag[tA] = (f1 <= Y[tA]) ? 1 : 0;
                    if (hasB) {
                        float f2 = scv[tB] + s2;
                        scv[tB] = f2; base[tB] = f2; flag[tB] = (f2 <= Y[tB]) ? 1 : 0;
                    }
                }
            }
        }
        __syncthreads();
    }
}

template<int CHV>
__global__ __launch_bounds__(NTHR, 4)
void sftrl_v4(const float* __restrict__ A, const float* __restrict__ Y,
              float* __restrict__ out, char* __restrict__ ws)
{
    const int tid = threadIdx.x, lane = tid & 63, wv = tid >> 6, bid = blockIdx.x;
    const int gw = bid * 16 + wv;

    int*   ctl    = (int*)(ws + O_CTL);
    int*   bar    = (int*)(ws + 128);
    int*   gen    = (int*)(ws + 192);
    int*   counts = (int*)(ws + O_CNT);
    int*   accT   = (int*)(ws + O_ACCT);
    float* accK   = (float*)(ws + O_ACCK);
    int*   ttime  = (int*)(ws + O_TTIME);
    float* Bt     = (float*)(ws + O_BT);
    float* base   = (float*)(ws + O_BASE);
    float* scv    = (float*)(ws + O_SCV);
    int*   flag   = (int*)(ws + O_FLAG);
    int*   cl0    = (int*)(ws + O_CL0);
    int*   LA     = (int*)(ws + O_LA);
    int*   LB     = (int*)(ws + O_LB);
    int*   chT    = (int*)(ws + O_CHT);
    float* chB    = (float*)(ws + O_CHB);
    float* chS    = (float*)(ws + O_CHS);
    float* D      = (float*)(ws + O_D);

    __shared__ __attribute__((aligned(16))) float SH[32832];
    __shared__ float s_rotA[64], s_rotB[64];
    __shared__ int   s_prt[64];
    __shared__ float s_S[64], s_Ss[64];
    __shared__ int   s_perm[64], s_misc[2];
    __shared__ float accL[CHV], bbL[CHV];
    __shared__ int   s_red[16];
    __shared__ int   s_imin, s_cnt;
    __shared__ int   accTl[64];
    __shared__ float accKl[64];

    // ---------------- P0a: init + per-block candidate counts ----------------
    const int rb = (NDATA + NBLK - 1) / NBLK;
    int r0 = min(bid * rb, NDATA), r1 = min(r0 + rb, NDATA);
    if (tid == 0) s_cnt = 0;
    __syncthreads();
    for (int t = r0 + tid; t < r1; t += NTHR) {
        base[t] = 0.f; scv[t] = 0.f;
        int f = (0.f <= Y[t]) ? 1 : 0;
        flag[t] = f;
        if (f) atomicAdd(&s_cnt, 1);
    }
    for (int i = bid * NTHR + tid; i < TWO_M * DFEAT; i += NBLK * NTHR) Bt[i] = 0.f;
    if (bid == 0 && tid < 16) ctl[tid] = 0;
    __syncthreads();
    if (tid == 0) counts[bid] = s_cnt;
    gbar(bar, gen);

    // ---------------- P0b: scatter cl0 (sorted) ----------------
    int ncand;
    {
        int pre, tot;
        counts_scan(counts, bid, lane, &pre, &tot);
        ncand = tot;
        if (wv == 0) {
            int dst = pre;
            for (int w0 = r0; w0 < r1; w0 += 64) {
                int t = w0 + lane;
                int fl = (t < r1) ? flag[t] : 0;
                unsigned long long mb = __ballot(fl);
                int pos = (int)__popcll(mb & ((1ull << lane) - 1ull));
                if (fl) cl0[dst + pos] = t;
                dst += (int)__popcll(mb);
            }
        }
    }
    gbar(bar, gen);

    // ---------------- P0c: first chunk prep ----------------
    int* listCur = cl0;
    int  lenCur  = ncand;
    phase_prepare<CHV>(A, Y, scv, flag, listCur, lenCur, accT, accK, 0,
                       chT, chB, chS, D, counts, SH, &s_cnt, bid, tid, wv, lane, gw);
    gbar(bar, gen);

    int fin_hi = -1, seg_lo = 1;

    for (;;) {
        int chunkLen = min(lenCur, CHV);
        int* listNxt = (listCur == LA) ? LB : LA;

        // ---------------- P1: scatter || resolve ----------------
        int tailTotal = scatter_and_total<CHV>(listCur, lenCur, flag, counts, listNxt,
                                               bid, tid, wv, lane);
        if (bid == 0)
            resolve_blk0<CHV>(A, Bt, ttime, chT, chB, chS, D, ctl, accT, accK,
                              chunkLen, tailTotal, accL, bbL, s_red, &s_imin,
                              accTl, accKl, tid, wv, lane);
        gbar(bar, gen);

        int nacc = ctl[C_NACC], rc = ctl[C_RC], shr = ctl[C_SHR], done = ctl[C_DONE];
        if (done) {
            finalize_range(A, base, Bt, ttime, out, fin_hi + 1, NDATA - 1, seg_lo, rc, gw, lane);
            return;
        }
        if (shr) {
            int ts = ctl[C_TS];
            // ---- P2s: finalize the closing segment with OLD Bt ----
            finalize_range(A, base, Bt, ttime, out, fin_hi + 1, ts, seg_lo, rc - 1, gw, lane);
            gbar(bar, gen);
            // ---- P3s: blk0 jacobi || others pre-build post-shrink chunk ----
            int cstart = lbound(cl0, ncand, ts);
            int clen2 = min(ncand - cstart, CHV);
            if (bid == 0) {
                jacobi_shrink(Bt, ctl, SH, s_rotA, s_rotB, s_prt, s_S, s_Ss, s_perm, s_misc, tid);
            } else {
                if (bid == 1) {
                    for (int i = tid; i < clen2; i += NTHR) {
                        int t = cl0[cstart + i];
                        chT[i] = t; chB[i] = Y[t];
                    }
                }
                build_D<CHV>(A, cl0 + cstart, clen2, D, (bid - 1) * 16 + wv, 255 * 16, lane);
            }
            gbar(bar, gen);
            int rcn = ctl[C_RCA];
            seg_lo = rcn + 1; fin_hi = ts;
            // ---- P4s: recompute scv/base/flag for t > ts with NEW Bt ----
            recompute_rows(A, Y, Bt, scv, base, flag, ts, SH, tid, wv, lane, gw);
            gbar(bar, gen);
            // ---- P4s2: chunk meta + tail counts ----
            listCur = cl0 + cstart; lenCur = ncand - cstart;
            for (int i = bid * NTHR + tid; i < clen2; i += NBLK * NTHR) {
                int t = chT[i];
                chS[i] = flag[t] ? scv[t] : BIGF;
            }
            {
                int tailLen = lenCur > CHV ? lenCur - CHV : 0;
                int ts2 = (tailLen + NBLK - 1) / NBLK;
                int e0 = min(bid * ts2, tailLen), e1 = min(e0 + ts2, tailLen);
                if (tid == 0) s_cnt = 0;
                __syncthreads();
                for (int e = e0 + tid; e < e1; e += NTHR) {
                    int t = listCur[CHV + e];
                    if (flag[t]) atomicAdd(&s_cnt, 1);
                }
                __syncthreads();
                if (tid == 0) counts[bid] = s_cnt;
            }
            gbar(bar, gen);
            continue;
        }
        // ---------------- P2: fold + compact-count + next chunk prep ----------------
        int lenNxt = tailTotal;
        phase_prepare<CHV>(A, Y, scv, flag, listNxt, lenNxt, accT, accK, nacc,
                           chT, chB, chS, D, counts, SH, &s_cnt, bid, tid, wv, lane, gw);
        gbar(bar, gen);
        listCur = listNxt; lenCur = lenNxt;
    }
}

extern "C" void kernel_launch(void* const* d_in, const int* in_sizes, int n_in,
                              void* d_out, int out_size, void* d_ws, size_t ws_size,
                              hipStream_t stream) {
    (void)in_sizes; (void)n_in; (void)out_size;
    const float* A = (const float*)d_in[0];
    const float* Y = (const float*)d_in[1];
    float* out = (float*)d_out;
    char* ws = (char*)d_ws;

    hipMemsetAsync(ws, 0, 256, stream);   // ctl + bar + gen

    void* kargs[] = { (void*)&A, (void*)&Y, (void*)&out, (void*)&ws };
    size_t need1024 = (size_t)O_D + (size_t)4 * 1024 * 1024;
    if (ws_size >= need1024) {
        hipLaunchCooperativeKernel((void*)sftrl_v4<1024>, dim3(NBLK), dim3(NTHR),
                                   kargs, 0, stream);
    } else {
        hipLaunchCooperativeKernel((void*)sftrl_v4<384>, dim3(NBLK), dim3(NTHR),
                                   kargs, 0, stream);
    }
}

// Round 10
// 1310.465 us; speedup vs baseline: 3.1090x; 3.1090x over previous
//
#include <hip/hip_runtime.h>
#include <hip/hip_cooperative_groups.h>
#include <math.h>

namespace cg = cooperative_groups;

#define NDATA   20000
#define DFEAT   1024
#define TWO_M   64
#define MM      32
#define ETA_F   1e-4f
#define THRES_F 1e-12f
#define NSWEEP  8
#define NBLK    128
#define NTHR    1024
#define NW      (NBLK*(NTHR/64))

// ---- ws layout (bytes) ----
#define O_CTL   0                  // int[16]: [0]=C_RCA; [8..11] winner ring (memset 0x7F)
#define O_TT    256                // int[64]   trigger time of column j
#define O_BT    512                // float[64*1024] columns of B (row j = col j)
#define O_BASE  (512 + 262144)     // float[20000] segment-start scalar
#define O_SCV   (O_BASE + 80000)   // float[20000] running scalar (alive rows)
#define O_FLAG  (O_SCV + 80000)    // int[20000]   1 = still-possible trigger
#define C_RCA   0
#define RS(k)   (8 + ((k) & 3))    // winner-ring slot for winner k

// jacobi LDS mapping inside SH[32832]
#define TG(r,c)     SH[(r)*257 + (c)]
#define SG(cb,idx)  SH[16448 + (cb)*4096 + (idx)]
#define SU(cb,idx)  SH[24640 + (cb)*4096 + (idx)]

// interleaved lane slicing: 16B/lane stride, coalesced + LDS-conflict-free
#define LD_SLICE(P,v0,v1,v2,v3) do { v0=(P)[lane]; v1=(P)[lane+64]; v2=(P)[lane+128]; v3=(P)[lane+192]; } while(0)

__device__ __forceinline__ float wave_sum(float v) {
    v += __shfl_xor(v, 1);  v += __shfl_xor(v, 2);  v += __shfl_xor(v, 4);
    v += __shfl_xor(v, 8);  v += __shfl_xor(v, 16); v += __shfl_xor(v, 32);
    return v;
}
__device__ __forceinline__ int wave_min_i(int v) {
    v = min(v, __shfl_xor(v, 1));  v = min(v, __shfl_xor(v, 2));
    v = min(v, __shfl_xor(v, 4));  v = min(v, __shfl_xor(v, 8));
    v = min(v, __shfl_xor(v, 16)); v = min(v, __shfl_xor(v, 32));
    return v;
}
__device__ __forceinline__ void pair_from(int p, int &a, int &b) {
    int a_ = 0, rem = p;
    while (rem >= 64 - a_) { rem -= 64 - a_; ++a_; }
    a = a_; b = a_ + rem;
}
__device__ __forceinline__ float dot16(float4 x0, float4 x1, float4 x2, float4 x3,
                                       float4 y0, float4 y1, float4 y2, float4 y3) {
    float d = x0.x*y0.x + x0.y*y0.y + x0.z*y0.z + x0.w*y0.w;
    d += x1.x*y1.x + x1.y*y1.y + x1.z*y1.z + x1.w*y1.w;
    d += x2.x*y2.x + x2.y*y2.y + x2.z*y2.z + x2.w*y2.w;
    d += x3.x*y3.x + x3.y*y3.y + x3.z*y3.z + x3.w*y3.w;
    return d;
}

// out[t] = base[t] + sum_{j in [jlo,jhi], ttime[j] < t} (Bt_j . alpha_t)^2
// Columns staged in LDS (halves of <=32 = 128 KB), single streaming pass over A per half.
__device__ void finalize_segment(const float* __restrict__ A, const float* __restrict__ base,
                                 const float* __restrict__ Bt, const int* __restrict__ ttime,
                                 float* __restrict__ out,
                                 int lo, int hi, int jlo, int jhi,
                                 float* SH, int* s_tt, int tid, int wv, int lane, int gw)
{
    int ncols = jhi - jlo + 1;
    if (ncols <= 0) {
        for (int t = lo + gw; t <= hi; t += NW)
            if (lane == 0) out[t] = base[t];
        return;
    }
    for (int h0 = jlo; h0 <= jhi; h0 += 32) {
        int nh = min(32, jhi - h0 + 1);
        __syncthreads();
        float4* S4w = (float4*)SH;
        for (int cc = wv; cc < nh; cc += 16) {
            const float4* Bj = (const float4*)(Bt + (size_t)(h0 + cc) * DFEAT);
            for (int q = 0; q < 4; ++q) S4w[cc * 256 + lane + 64 * q] = Bj[lane + 64 * q];
        }
        if (tid < nh) s_tt[tid] = ttime[h0 + tid];
        __syncthreads();
        const float4* S4 = (const float4*)SH;
        for (int t = lo + gw; t <= hi; t += NW) {
            const float4* At = (const float4*)(A + (size_t)t * DFEAT);
            float4 a0, a1, a2, a3; LD_SLICE(At, a0, a1, a2, a3);
            float o = (h0 == jlo) ? base[t] : out[t];
            for (int s = 0; s < nh; ++s) {
                if (s_tt[s] >= t) break;              // ttimes ascending within segment
                float d = dot16(a0, a1, a2, a3,
                                S4[s*256+lane], S4[s*256+lane+64],
                                S4[s*256+lane+128], S4[s*256+lane+192]);
                d = wave_sum(d);
                o += d * d;
            }
            if (lane == 0) out[t] = o;
        }
    }
}

// block-0 FD shrink: Gram -> tournament Jacobi -> sort -> remix Bt (unchanged, proven-compiling)
__device__ void jacobi_shrink(float* __restrict__ Bt, int* __restrict__ ctl, float* SH,
                              float* s_rotA, float* s_rotB, int* s_prt,
                              float* s_S, float* s_Ss, int* s_perm, int* s_misc, int tid)
{
    float acc0 = 0.f, acc1 = 0.f, acc2 = 0.f;
    int a0i, b0i, a1i, b1i, a2i, b2i;
    pair_from(tid, a0i, b0i);
    pair_from(tid + 1024, a1i, b1i);
    pair_from((tid < 32) ? (tid + 2048) : 0, a2i, b2i);
    for (int c = 0; c < 4; ++c) {
        __syncthreads();
        for (int q = tid; q < 64 * 64; q += NTHR) {
            int jj = q >> 6, d4 = q & 63;
            float4 v = ((const float4*)(Bt + (size_t)jj * DFEAT + c * 256))[d4];
            TG(jj, d4*4+0) = v.x; TG(jj, d4*4+1) = v.y;
            TG(jj, d4*4+2) = v.z; TG(jj, d4*4+3) = v.w;
        }
        __syncthreads();
        for (int dd = 0; dd < 256; ++dd) {
            acc0 += TG(a0i, dd) * TG(b0i, dd);
            acc1 += TG(a1i, dd) * TG(b1i, dd);
            acc2 += TG(a2i, dd) * TG(b2i, dd);
        }
    }
    SG(0, a0i*64+b0i) = acc0; SG(0, b0i*64+a0i) = acc0;
    SG(0, a1i*64+b1i) = acc1; SG(0, b1i*64+a1i) = acc1;
    if (tid < 32) { SG(0, a2i*64+b2i) = acc2; SG(0, b2i*64+a2i) = acc2; }
    for (int e4 = 0; e4 < 4; ++e4) {
        int e = tid + e4 * 1024;
        SU(0, e) = ((e >> 6) == (e & 63)) ? 1.f : 0.f;
    }
    __syncthreads();

    int cur = 0;
    for (int sw = 0; sw < NSWEEP; ++sw) {
        for (int r = 0; r < 63; ++r) {
            if (tid < 32) {
                int p_, q_;
                if (tid == 0) { p_ = 63; q_ = r; }
                else { p_ = (r + tid) % 63; q_ = (r + 63 - tid) % 63; }
                float gpp = SG(cur, p_*64+p_);
                float gqq = SG(cur, q_*64+q_);
                float gpq = SG(cur, p_*64+q_);
                float cc = 1.f, sn = 0.f;
                if (fabsf(gpq) > 1e-20f) {
                    float tau = (gqq - gpp) / (2.f * gpq);
                    float tt  = (tau >= 0.f ? 1.f : -1.f) / (fabsf(tau) + sqrtf(1.f + tau * tau));
                    cc = 1.f / sqrtf(1.f + tt * tt);
                    sn = tt * cc;
                }
                s_rotA[p_] = cc; s_rotB[p_] = -sn; s_prt[p_] = q_;
                s_rotA[q_] = cc; s_rotB[q_] = sn;  s_prt[q_] = p_;
            }
            __syncthreads();
            float ng[4], nu[4];
            for (int e4 = 0; e4 < 4; ++e4) {
                int e = tid + e4 * 1024;
                int row = e >> 6, col = e & 63;
                int pr = s_prt[row], pc = s_prt[col];
                float ar = s_rotA[row], br = s_rotB[row];
                float ac = s_rotA[col], bc = s_rotB[col];
                ng[e4] = ar*ac*SG(cur, row*64+col) + br*ac*SG(cur, pr*64+col)
                       + ar*bc*SG(cur, row*64+pc)  + br*bc*SG(cur, pr*64+pc);
                nu[e4] = ac*SU(cur, row*64+col) + bc*SU(cur, row*64+pc);
            }
            for (int e4 = 0; e4 < 4; ++e4) {
                int e = tid + e4 * 1024;
                SG(cur ^ 1, e) = ng[e4];
                SU(cur ^ 1, e) = nu[e4];
            }
            __syncthreads();
            cur ^= 1;
        }
    }

    if (tid < 64) {
        float lam = SG(cur, tid*64+tid);
        if (lam <= THRES_F) lam = 0.f;
        s_S[tid] = lam;
    }
    __syncthreads();
    if (tid < 64) {
        float my = s_S[tid];
        int rank = 0;
        for (int i = 0; i < 64; ++i) {
            float o = s_S[i];
            rank += ((o > my) || (o == my && i < tid)) ? 1 : 0;
        }
        s_perm[rank] = tid;
        s_Ss[rank]   = my;
    }
    __syncthreads();
    if (tid == 0) {
        int nz = 0;
        for (int i = 0; i < 64; ++i) nz += (s_Ss[i] > 0.f) ? 1 : 0;
        s_misc[0] = nz;
        s_misc[1] = (nz >= MM) ? 1 : 0;
    }
    __syncthreads();
    const int nnz = s_misc[0];
    const int ge  = s_misc[1];
    const float S32 = s_Ss[MM];

    for (int e4 = 0; e4 < 4; ++e4) {
        int e = tid + e4 * 1024;
        int kk = e >> 6, jn = e & 63;
        float Sj = s_Ss[jn];
        float f;
        if (ge) f = (jn < MM - 1 && Sj > 0.f) ? sqrtf(fmaxf(Sj - S32, 0.f) / Sj) : 0.f;
        else    f = (jn < nnz) ? 1.f : 0.f;
        SG(0, kk*64+jn) = SU(cur, kk*64 + s_perm[jn]) * f;
    }
    __syncthreads();

    for (int c = 0; c < 4; ++c) {
        __syncthreads();
        for (int q = tid; q < 64 * 64; q += NTHR) {
            int jj = q >> 6, d4 = q & 63;
            float4 v = ((const float4*)(Bt + (size_t)jj * DFEAT + c * 256))[d4];
            TG(jj, d4*4+0) = v.x; TG(jj, d4*4+1) = v.y;
            TG(jj, d4*4+2) = v.z; TG(jj, d4*4+3) = v.w;
        }
        __syncthreads();
        for (int q = tid; q < 64 * 256; q += NTHR) {
            int dd = q & 255, jn = q >> 8;
            float sum = 0.f;
            for (int kk = 0; kk < 64; ++kk)
                sum += TG(kk, dd) * SG(0, kk*64+jn);
            Bt[(size_t)jn * DFEAT + c * 256 + dd] = sum;
        }
    }
    __syncthreads();
    if (tid == 0) ctl[C_RCA] = ge ? (MM - 1) : nnz;
}

// post-shrink: rebuild scv/base/flag for t > ts with NEW Bt (LDS-staged halves) + min-scan
__device__ void recompute_rows(const float* __restrict__ A, const float* __restrict__ Y,
                               const float* __restrict__ Bt,
                               float* __restrict__ scv, float* __restrict__ base,
                               int* __restrict__ flag, int ts,
                               float* SH, int* s_min, int tid, int wv, int lane, int gw)
{
    int nrows = NDATA - 1 - ts;
    int npair = (nrows + 1) >> 1;
    for (int h = 0; h < 2; ++h) {
        __syncthreads();
        {
            const float4* B4 = (const float4*)Bt;
            float4* S4w = (float4*)SH;
            for (int q = 0; q < 4; ++q) {
                S4w[wv * 256 + lane + 64*q]      = B4[(size_t)(h*32 + wv) * 256 + lane + 64*q];
                S4w[(wv+16) * 256 + lane + 64*q] = B4[(size_t)(h*32 + wv + 16) * 256 + lane + 64*q];
            }
        }
        __syncthreads();
        const float4* S4 = (const float4*)SH;
        for (int p = gw; p < npair; p += NW) {
            int tA = ts + 1 + 2*p;
            int tB = tA + 1;
            bool hasB = tB < NDATA;
            const float4* Aa = (const float4*)(A + (size_t)tA * DFEAT);
            float4 x0, x1, x2, x3; LD_SLICE(Aa, x0, x1, x2, x3);
            float4 y0 = make_float4(0,0,0,0), y1 = y0, y2 = y0, y3 = y0;
            if (hasB) {
                const float4* Ab = (const float4*)(A + (size_t)tB * DFEAT);
                LD_SLICE(Ab, y0, y1, y2, y3);
            }
            float s1 = 0.f, s2 = 0.f;
            for (int j = 0; j < 32; ++j) {
                float4 b0 = S4[j*256+lane],     b1 = S4[j*256+lane+64],
                       b2 = S4[j*256+lane+128], b3 = S4[j*256+lane+192];
                float d1 = dot16(x0,x1,x2,x3,b0,b1,b2,b3);
                d1 = wave_sum(d1);
                s1 += d1 * d1;
                float d2 = dot16(y0,y1,y2,y3,b0,b1,b2,b3);
                d2 = wave_sum(d2);
                s2 += d2 * d2;
            }
            if (lane == 0) {
                if (h == 0) {
                    scv[tA] = s1;
                    if (hasB) scv[tB] = s2;
                } else {
                    float f1 = scv[tA] + s1;
                    scv[tA] = f1; base[tA] = f1;
                    int a1v = (f1 <= Y[tA]) ? 1 : 0;
                    flag[tA] = a1v;
                    if (a1v) atomicMin(s_min, tA);
                    if (hasB) {
                        float f2 = scv[tB] + s2;
                        scv[tB] = f2; base[tB] = f2;
                        int a2v = (f2 <= Y[tB]) ? 1 : 0;
                        flag[tB] = a2v;
                        if (a2v) atomicMin(s_min, tB);
                    }
                }
            }
        }
        __syncthreads();
    }
}

__global__ __launch_bounds__(NTHR, 4)
void sftrl_v5(const float* __restrict__ A, const float* __restrict__ Y,
              float* __restrict__ out, char* __restrict__ ws)
{
    cg::grid_group grid = cg::this_grid();
    const int tid = threadIdx.x, lane = tid & 63, wv = tid >> 6, bid = blockIdx.x;
    const int gw = bid * (NTHR / 64) + wv;

    int*   ctl   = (int*)(ws + O_CTL);
    int*   ttime = (int*)(ws + O_TT);
    float* Bt    = (float*)(ws + O_BT);
    float* base  = (float*)(ws + O_BASE);
    float* scv   = (float*)(ws + O_SCV);
    int*   flag  = (int*)(ws + O_FLAG);

    __shared__ __attribute__((aligned(16))) float SH[32832];
    __shared__ float s_rotA[64], s_rotB[64];
    __shared__ int   s_prt[64];
    __shared__ float s_S[64], s_Ss[64];
    __shared__ int   s_perm[64], s_misc[2];
    __shared__ int   s_tt[32];
    __shared__ int   s_min;

    // ---------------- bootstrap: init + initial min-scan (winner 0 -> ring slot RS(0)) ----
    int tmin = NDATA;
    for (int t = bid * NTHR + tid; t < NDATA; t += NBLK * NTHR) {
        base[t] = 0.f; scv[t] = 0.f;
        int f = (0.f <= Y[t]) ? 1 : 0;         // scalar starts at 0
        flag[t] = f;
        if (f) tmin = min(tmin, t);
    }
    for (int i = bid * NTHR + tid; i < TWO_M * DFEAT; i += NBLK * NTHR) Bt[i] = 0.f;
    tmin = wave_min_i(tmin);
    if (tid == 0) s_min = NDATA;
    __syncthreads();
    if (lane == 0) atomicMin(&s_min, tmin);
    __syncthreads();
    if (tid == 0 && s_min < NDATA) atomicMin(&ctl[RS(0)], s_min);
    grid.sync();

    int ts = ctl[RS(0)];
    int rc = 0, fin_hi = -1, seg_lo = 1, r = 0;

    // ---------------- main loop: ONE grid sync per trigger ----------------
    for (;;) {
        if (ts >= NDATA) {
            // no more triggers: finalize the open segment, done
            finalize_segment(A, base, Bt, ttime, out, fin_hi + 1, NDATA - 1,
                             seg_lo, rc, SH, s_tt, tid, wv, lane, gw);
            return;
        }

        // accept trigger ts (all blocks compute identical kap from global state)
        float sc  = scv[ts];
        float b   = Y[ts];
        float kap = sqrtf(2.f * ETA_F * (b - sc));
        rc += 1;
        if (bid == 0) {                                   // append column rc
            Bt[(size_t)rc * DFEAT + tid] = kap * A[(size_t)ts * DFEAT + tid];
            if (tid == 0) ttime[rc] = ts;
        }

        if (rc == TWO_M - 1) {
            // ============ SHRINK (statistically unreachable; kept correct) ============
            int tso = ts;
            // 1) finalize closing segment with OLD Bt (col rc excluded: ttime==ts >= all t<=ts)
            finalize_segment(A, base, Bt, ttime, out, fin_hi + 1, tso,
                             seg_lo, rc - 1, SH, s_tt, tid, wv, lane, gw);
            grid.sync();                                  // reads done before Bt rewrite
            // 2) block-0 Jacobi eigen-shrink
            if (bid == 0)
                jacobi_shrink(Bt, ctl, SH, s_rotA, s_rotB, s_prt, s_S, s_Ss,
                              s_perm, s_misc, tid);
            grid.sync();                                  // B_new + C_RCA visible
            int rcn = ctl[C_RCA];
            // 3) rebuild scv/base/flag for t > tso with NEW Bt + find next winner
            if (tid == 0) s_min = NDATA;
            __syncthreads();
            recompute_rows(A, Y, Bt, scv, base, flag, tso, SH, &s_min,
                           tid, wv, lane, gw);
            __syncthreads();
            if (tid == 0) {
                if (s_min < NDATA) atomicMin(&ctl[RS(r + 1)], s_min);
                if (bid == 0) ctl[RS(r + 2)] = 0x7F7F7F7F;   // ring reset (>=2 syncs past)
            }
            grid.sync();
            ts = ctl[RS(r + 1)]; r += 1;
            rc = rcn; fin_hi = tso; seg_lo = rcn + 1;
            continue;
        }

        // ---- fold round: rank-1 correct alive candidates, kill, find next winner ----
        if (tid == 0) s_min = NDATA;
        __syncthreads();
        const float4* Ast = (const float4*)(A + (size_t)ts * DFEAT);
        float4 as0, as1, as2, as3; LD_SLICE(Ast, as0, as1, as2, as3);
        int wmin = NDATA;
        for (int t = ts + 1 + gw; t < NDATA; t += NW) {
            if (!flag[t]) continue;                       // wave-uniform branch
            const float4* At = (const float4*)(A + (size_t)t * DFEAT);
            float4 a0, a1, a2, a3; LD_SLICE(At, a0, a1, a2, a3);
            float d = dot16(as0, as1, as2, as3, a0, a1, a2, a3);
            d = wave_sum(d);
            float v  = kap * d;
            float sc2 = scv[t] + v * v;
            if (sc2 <= Y[t]) {                            // still a candidate
                if (lane == 0) scv[t] = sc2;
                wmin = min(wmin, t);
            } else {                                      // monotone: dead forever
                if (lane == 0) flag[t] = 0;
            }
        }
        if (lane == 0) atomicMin(&s_min, wmin);
        __syncthreads();
        if (tid == 0) {
            if (s_min < NDATA) atomicMin(&ctl[RS(r + 1)], s_min);
            if (bid == 0) ctl[RS(r + 2)] = 0x7F7F7F7F;    // ring reset (>=2 syncs past)
        }
        grid.sync();                                      // ---- the ONE sync ----
        ts = ctl[RS(r + 1)]; r += 1;
    }
}

extern "C" void kernel_launch(void* const* d_in, const int* in_sizes, int n_in,
                              void* d_out, int out_size, void* d_ws, size_t ws_size,
                              hipStream_t stream) {
    (void)in_sizes; (void)n_in; (void)ws_size; (void)out_size;
    const float* A = (const float*)d_in[0];
    const float* Y = (const float*)d_in[1];
    float* out = (float*)d_out;
    char* ws = (char*)d_ws;

    // preset ctl[0..15]: C_RCA + winner ring to +large for atomicMin
    hipMemsetAsync(ws, 0x7F, 64, stream);

    void* kargs[] = { (void*)&A, (void*)&Y, (void*)&out, (void*)&ws };
    hipLaunchCooperativeKernel((void*)sftrl_v5, dim3(NBLK), dim3(NTHR),
                               kargs, 0, stream);
}